// Round 1
// baseline (435.535 us; speedup 1.0000x reference)
//
#include <hip/hip_runtime.h>

#define NODES 40000
#define NEDGE 640000
#define HD 128

// ---------------- CSR build ----------------

__global__ void hist_kernel(const int* __restrict__ dst, int* __restrict__ counts, int E) {
    int e = blockIdx.x * blockDim.x + threadIdx.x;
    if (e < E) atomicAdd(&counts[dst[e]], 1);
}

// single-block scan: rowptr (exclusive), cursor copy, dis = rsqrt(deg+1)
__global__ __launch_bounds__(1024) void scan_kernel(const int* __restrict__ counts,
                                                    int* __restrict__ rowptr,
                                                    int* __restrict__ cursor,
                                                    float* __restrict__ dis,
                                                    int N) {
    __shared__ int wsum[16];
    int t = threadIdx.x;
    int lane = t & 63;
    int w = t >> 6;
    int carry = 0;
    for (int base = 0; base < N; base += 1024) {
        int idx = base + t;
        int c = (idx < N) ? counts[idx] : 0;
        int v = c;
        #pragma unroll
        for (int d = 1; d < 64; d <<= 1) {
            int u = __shfl_up(v, d, 64);
            if (lane >= d) v += u;
        }
        if (lane == 63) wsum[w] = v;
        __syncthreads();
        int off = carry;
        for (int j = 0; j < w; ++j) off += wsum[j];
        if (idx < N) {
            int excl = off + v - c;
            rowptr[idx] = excl;
            cursor[idx] = excl;
            dis[idx] = rsqrtf((float)c + 1.0f);
        }
        int tot = 0;
        #pragma unroll
        for (int j = 0; j < 16; ++j) tot += wsum[j];
        carry += tot;
        __syncthreads();
    }
    if (t == 0) rowptr[N] = carry;
}

__global__ void fill_kernel(const int* __restrict__ src, const int* __restrict__ dst,
                            int* __restrict__ cursor, int* __restrict__ colv, int E) {
    int e = blockIdx.x * blockDim.x + threadIdx.x;
    if (e < E) {
        int d = dst[e];
        int pos = atomicAdd(&cursor[d], 1);
        colv[pos] = src[e];
    }
}

// ---------------- small dense helpers ----------------

// C[128,128] = A[128,128] @ B[128,128]
__global__ void small_mm_kernel(const float* __restrict__ A, const float* __restrict__ B,
                                float* __restrict__ C) {
    int idx = blockIdx.x * 256 + threadIdx.x;   // 64 blocks x 256
    int i = idx >> 7, j = idx & 127;
    float s = 0.f;
    for (int k = 0; k < 128; ++k) s += A[i * 128 + k] * B[k * 128 + j];
    C[idx] = s;
}

// cvec[j] = sum_k b_in[k] * W1[k,j]
__global__ void cvec_kernel(const float* __restrict__ bin, const float* __restrict__ W1,
                            float* __restrict__ cvec) {
    int j = threadIdx.x;  // 128 threads
    float s = 0.f;
    for (int k = 0; k < 128; ++k) s += bin[k] * W1[k * 128 + j];
    cvec[j] = s;
}

// ---------------- big matmul: C[M,128] = A[M,128] @ B[128,128] ----------------
// block: 256 threads (16x16), tile 64 rows x 128 cols, each thread 4x8 acc.
#define MM_BK 32
__global__ __launch_bounds__(256) void mm_kernel(const float* __restrict__ A,
                                                 const float* __restrict__ B,
                                                 float* __restrict__ C) {
    __shared__ alignas(16) float At[MM_BK][68];    // transposed A tile [k][r]
    __shared__ alignas(16) float Bs[MM_BK][132];   // B tile [k][c]
    int t = threadIdx.x;
    int tx = t & 15;      // col group: cols 8*tx .. 8*tx+7
    int ty = t >> 4;      // row group: rows 4*ty .. 4*ty+3
    int row0 = blockIdx.x * 64;
    float acc[4][8];
    #pragma unroll
    for (int r = 0; r < 4; ++r)
        #pragma unroll
        for (int c = 0; c < 8; ++c) acc[r][c] = 0.f;

    for (int k0 = 0; k0 < 128; k0 += MM_BK) {
        // stage A: 64 rows x 32 k = 2048 floats -> 2 float4 / thread, transposed
        #pragma unroll
        for (int i = 0; i < 2; ++i) {
            int fi = t * 2 + i;              // 0..511
            int r = fi >> 3;                 // 8 float4 per row
            int kk = (fi & 7) * 4;
            float4 v = *(const float4*)(A + (size_t)(row0 + r) * 128 + k0 + kk);
            At[kk + 0][r] = v.x;
            At[kk + 1][r] = v.y;
            At[kk + 2][r] = v.z;
            At[kk + 3][r] = v.w;
        }
        // stage B: 32 k x 128 c = 4096 floats -> 4 float4 / thread
        #pragma unroll
        for (int i = 0; i < 4; ++i) {
            int fi = t * 4 + i;              // 0..1023
            int kk = fi >> 5;                // 32 float4 per k row
            int c = (fi & 31) * 4;
            *(float4*)&Bs[kk][c] = *(const float4*)(B + (size_t)(k0 + kk) * 128 + c);
        }
        __syncthreads();
        #pragma unroll 8
        for (int kk = 0; kk < MM_BK; ++kk) {
            float4 a = *(const float4*)&At[kk][ty * 4];
            float4 b0 = *(const float4*)&Bs[kk][tx * 8];
            float4 b1 = *(const float4*)&Bs[kk][tx * 8 + 4];
            float av[4] = {a.x, a.y, a.z, a.w};
            float bv[8] = {b0.x, b0.y, b0.z, b0.w, b1.x, b1.y, b1.z, b1.w};
            #pragma unroll
            for (int r = 0; r < 4; ++r)
                #pragma unroll
                for (int c = 0; c < 8; ++c) acc[r][c] = fmaf(av[r], bv[c], acc[r][c]);
        }
        __syncthreads();
    }
    #pragma unroll
    for (int r = 0; r < 4; ++r) {
        size_t row = (size_t)(row0 + ty * 4 + r);
        float4 o0 = {acc[r][0], acc[r][1], acc[r][2], acc[r][3]};
        float4 o1 = {acc[r][4], acc[r][5], acc[r][6], acc[r][7]};
        *(float4*)(C + row * 128 + tx * 8) = o0;
        *(float4*)(C + row * 128 + tx * 8 + 4) = o1;
    }
}

// ---------------- GCN aggregation: one wave per dst node ----------------
// out[i] = relu( sum_e norm_e * hw[src_e] + dis_i^2 * hw[i] + sumnorm * cvec + bias )
__global__ __launch_bounds__(256) void agg_kernel(const float* __restrict__ hw,
                                                  const float* __restrict__ dis,
                                                  const int* __restrict__ rowptr,
                                                  const int* __restrict__ colv,
                                                  const float* __restrict__ cvec,
                                                  const float* __restrict__ bias,
                                                  float* __restrict__ out, int N) {
    int wave = (int)((blockIdx.x * 256u + threadIdx.x) >> 6);
    int lane = threadIdx.x & 63;
    if (wave >= N) return;
    int i = wave;
    float di = dis[i];
    int beg = rowptr[i], end = rowptr[i + 1];
    const float2* __restrict__ hwv = (const float2*)hw;
    float sii = di * di;
    float2 hs = hwv[(size_t)i * 64 + lane];
    float a0 = sii * hs.x;
    float a1 = sii * hs.y;
    float sumnorm = sii;
    int e = beg;
    for (; e + 1 < end; e += 2) {
        int s0 = colv[e], s1 = colv[e + 1];
        float n0 = dis[s0] * di;
        float n1 = dis[s1] * di;
        float2 v0 = hwv[(size_t)s0 * 64 + lane];
        float2 v1 = hwv[(size_t)s1 * 64 + lane];
        a0 = fmaf(n0, v0.x, a0);
        a1 = fmaf(n0, v0.y, a1);
        a0 = fmaf(n1, v1.x, a0);
        a1 = fmaf(n1, v1.y, a1);
        sumnorm += n0 + n1;
    }
    if (e < end) {
        int s0 = colv[e];
        float n0 = dis[s0] * di;
        float2 v0 = hwv[(size_t)s0 * 64 + lane];
        a0 = fmaf(n0, v0.x, a0);
        a1 = fmaf(n0, v0.y, a1);
        sumnorm += n0;
    }
    float c0 = 0.f, c1 = 0.f;
    if (cvec) { c0 = cvec[2 * lane]; c1 = cvec[2 * lane + 1]; }
    float b0 = bias[2 * lane], b1 = bias[2 * lane + 1];
    float o0 = fmaxf(a0 + sumnorm * c0 + b0, 0.f);
    float o1 = fmaxf(a1 + sumnorm * c1 + b1, 0.f);
    float2 o = {o0, o1};
    ((float2*)out)[(size_t)i * 64 + lane] = o;
}

// ---------------- pooling: block of 256 nodes, register accumulation ----------------
__global__ __launch_bounds__(256) void pool_kernel(const float* __restrict__ h,
                                                   const int* __restrict__ batch,
                                                   float* __restrict__ pool, int N) {
    int t = threadIdx.x;
    int c = t & 127, half = t >> 7;
    int n0 = blockIdx.x * 256 + half * 128;
    int cur = -1;
    float acc = 0.f;
    for (int j = 0; j < 128; ++j) {
        int n = n0 + j;
        if (n >= N) break;
        int g = batch[n];
        float v = h[(size_t)n * 128 + c];
        if (g != cur) {
            if (cur >= 0) atomicAdd(&pool[cur * 128 + c], acc);
            cur = g;
            acc = 0.f;
        }
        acc += v;
    }
    if (cur >= 0) atomicAdd(&pool[cur * 128 + c], acc);
}

// ---------------- final MLP head ----------------
__device__ int lower_bound_dev(const int* __restrict__ a, int n, int x) {
    int lo = 0, hi = n;
    while (lo < hi) {
        int m = (lo + hi) >> 1;
        if (a[m] < x) lo = m + 1; else hi = m;
    }
    return lo;
}

__global__ __launch_bounds__(256) void final_kernel(const float* __restrict__ pool_sum,
                                                    const int* __restrict__ batch,
                                                    const float* __restrict__ Wf1,
                                                    const float* __restrict__ bf1,
                                                    const float* __restrict__ Wf2,
                                                    const float* __restrict__ bf2,
                                                    float* __restrict__ out, int N) {
    __shared__ float pooled[16][128];
    __shared__ float z[16][64];
    __shared__ int cnt[16];
    int t = threadIdx.x;
    if (t < 16) {
        int lo = lower_bound_dev(batch, N, t);
        int hi = lower_bound_dev(batch, N, t + 1);
        cnt[t] = hi - lo;
    }
    __syncthreads();
    for (int idx = t; idx < 2048; idx += 256) {
        int g = idx >> 7, c = idx & 127;
        float cn = (float)(cnt[g] > 1 ? cnt[g] : 1);
        pooled[g][c] = pool_sum[idx] / cn;
    }
    __syncthreads();
    for (int idx = t; idx < 1024; idx += 256) {
        int g = idx >> 6, j = idx & 63;
        float s = bf1[j];
        for (int k = 0; k < 128; ++k) s = fmaf(pooled[g][k], Wf1[k * 64 + j], s);
        z[g][j] = fmaxf(s, 0.f);
    }
    __syncthreads();
    if (t < 160) {
        int g = t / 10, k = t % 10;
        float s = bf2[k];
        for (int j = 0; j < 64; ++j) s = fmaf(z[g][j], Wf2[j * 10 + k], s);
        out[t] = s;
    }
}

// ---------------- launch ----------------

extern "C" void kernel_launch(void* const* d_in, const int* in_sizes, int n_in,
                              void* d_out, int out_size, void* d_ws, size_t ws_size,
                              hipStream_t stream) {
    const float* x    = (const float*)d_in[0];
    const int* edge   = (const int*)d_in[1];   // [2, E]: src = edge[0..E), dst = edge[E..2E)
    const int* batch  = (const int*)d_in[2];
    const float* W_in = (const float*)d_in[3];
    const float* b_in = (const float*)d_in[4];
    const float* W1   = (const float*)d_in[5];
    const float* b1   = (const float*)d_in[6];
    const float* W2   = (const float*)d_in[7];
    const float* b2   = (const float*)d_in[8];
    const float* Wf1  = (const float*)d_in[9];
    const float* bf1  = (const float*)d_in[10];
    const float* Wf2  = (const float*)d_in[11];
    const float* bf2  = (const float*)d_in[12];
    float* out = (float*)d_out;

    const int N = NODES, E = NEDGE;

    char* ws = (char*)d_ws;
    size_t off = 0;
    auto alloc = [&](size_t bytes) -> void* {
        void* p = ws + off;
        off += (bytes + 511) & ~(size_t)511;
        return p;
    };
    float* bufA   = (float*)alloc((size_t)N * 128 * 4);  // hw1, then hw2
    float* bufB   = (float*)alloc((size_t)N * 128 * 4);  // h1, then h2
    float* Wc     = (float*)alloc(128 * 128 * 4);
    float* cvec   = (float*)alloc(128 * 4);
    float* dis    = (float*)alloc((size_t)N * 4);
    int* rowptr   = (int*)alloc((size_t)(N + 1) * 4);
    int* cursor   = (int*)alloc((size_t)N * 4);
    int* counts   = (int*)alloc((size_t)N * 4);
    int* colbuf   = (int*)alloc((size_t)E * 4);
    float* pools  = (float*)alloc(16 * 128 * 4);

    hipMemsetAsync(counts, 0, (size_t)N * 4, stream);
    hipMemsetAsync(pools, 0, 16 * 128 * 4, stream);

    hist_kernel<<<(E + 255) / 256, 256, 0, stream>>>(edge + E, counts, E);
    scan_kernel<<<1, 1024, 0, stream>>>(counts, rowptr, cursor, dis, N);
    fill_kernel<<<(E + 255) / 256, 256, 0, stream>>>(edge, edge + E, cursor, colbuf, E);

    small_mm_kernel<<<64, 256, 0, stream>>>(W_in, W1, Wc);
    cvec_kernel<<<1, 128, 0, stream>>>(b_in, W1, cvec);

    // layer 1: hw1 = x @ (W_in W1); h1 = relu(S @ hw1 + sumnorm*cvec + b1)
    mm_kernel<<<N / 64, 256, 0, stream>>>(x, Wc, bufA);
    agg_kernel<<<N / 4, 256, 0, stream>>>(bufA, dis, rowptr, colbuf, cvec, b1, bufB, N);

    // layer 2: hw2 = h1 @ W2; h2 = relu(S @ hw2 + b2)
    mm_kernel<<<N / 64, 256, 0, stream>>>(bufB, W2, bufA);
    agg_kernel<<<N / 4, 256, 0, stream>>>(bufA, dis, rowptr, colbuf, nullptr, b2, bufB, N);

    // mean pool + MLP head
    pool_kernel<<<(N + 255) / 256, 256, 0, stream>>>(bufB, batch, pools, N);
    final_kernel<<<1, 256, 0, stream>>>(pools, batch, Wf1, bf1, Wf2, bf2, out, N);
}

// Round 2
// 314.906 us; speedup vs baseline: 1.3831x; 1.3831x over previous
//
#include <hip/hip_runtime.h>

#define NODES 40000
#define NEDGE 640000

typedef unsigned int uint;
typedef unsigned short ushort;
typedef __attribute__((ext_vector_type(8))) short short8;
typedef __attribute__((ext_vector_type(4))) float floatx4;

// ---- bf16 helpers (RNE) ----
__device__ inline ushort f2bf(float f) {
    uint u = __float_as_uint(f);
    uint r = (u + 0x7fffu + ((u >> 16) & 1u)) >> 16;
    return (ushort)r;
}
__device__ inline float bf_lo(uint u) { return __uint_as_float(u << 16); }
__device__ inline float bf_hi(uint u) { return __uint_as_float(u & 0xffff0000u); }

// ---------------- CSR build ----------------

__global__ void hist_kernel(const int* __restrict__ dst, int* __restrict__ counts, int E) {
    int e = blockIdx.x * blockDim.x + threadIdx.x;
    if (e < E) atomicAdd(&counts[dst[e]], 1);
}

// hierarchical scan: s1 block-reduce -> s2 scan block sums -> s3 per-block scan+scatter
__global__ __launch_bounds__(256) void s1_reduce(const int* __restrict__ counts,
                                                int* __restrict__ bsum, int N) {
    int idx = blockIdx.x * 256 + threadIdx.x;
    int c = (idx < N) ? counts[idx] : 0;
    #pragma unroll
    for (int d = 32; d; d >>= 1) c += __shfl_down(c, d, 64);
    __shared__ int ws[4];
    if ((threadIdx.x & 63) == 0) ws[threadIdx.x >> 6] = c;
    __syncthreads();
    if (threadIdx.x == 0) bsum[blockIdx.x] = ws[0] + ws[1] + ws[2] + ws[3];
}

__global__ __launch_bounds__(256) void s2_scan(const int* __restrict__ bsum,
                                               int* __restrict__ boff,
                                               int* __restrict__ rowptr_last, int B) {
    int t = threadIdx.x;
    int lane = t & 63, w = t >> 6;
    int c = (t < B) ? bsum[t] : 0;
    int v = c;
    #pragma unroll
    for (int d = 1; d < 64; d <<= 1) {
        int u = __shfl_up(v, d, 64);
        if (lane >= d) v += u;
    }
    __shared__ int ws[4];
    if (lane == 63) ws[w] = v;
    __syncthreads();
    int off = 0;
    for (int j = 0; j < w; ++j) off += ws[j];
    if (t < B) boff[t] = off + v - c;
    if (t == B - 1) rowptr_last[0] = off + v;
}

__global__ __launch_bounds__(256) void s3_scatter(const int* __restrict__ counts,
                                                  const int* __restrict__ boff,
                                                  int* __restrict__ rowptr,
                                                  int* __restrict__ cursor,
                                                  float* __restrict__ dis, int N) {
    int idx = blockIdx.x * 256 + threadIdx.x;
    int t = threadIdx.x, lane = t & 63, w = t >> 6;
    int c = (idx < N) ? counts[idx] : 0;
    int v = c;
    #pragma unroll
    for (int d = 1; d < 64; d <<= 1) {
        int u = __shfl_up(v, d, 64);
        if (lane >= d) v += u;
    }
    __shared__ int ws[4];
    if (lane == 63) ws[w] = v;
    __syncthreads();
    int off = boff[blockIdx.x];
    for (int j = 0; j < w; ++j) off += ws[j];
    if (idx < N) {
        int excl = off + v - c;
        rowptr[idx] = excl;
        cursor[idx] = excl;
        dis[idx] = rsqrtf((float)c + 1.0f);
    }
}

__global__ void fill_kernel(const int* __restrict__ src, const int* __restrict__ dst,
                            int* __restrict__ cursor, int* __restrict__ colv, int E) {
    int e = blockIdx.x * blockDim.x + threadIdx.x;
    if (e < E) {
        int d = dst[e];
        int pos = atomicAdd(&cursor[d], 1);
        colv[pos] = src[e];
    }
}

// ---------------- small dense helpers ----------------

// C[128,128] = A[128,128] @ B[128,128] (fp32, tiny)
__global__ void small_mm_kernel(const float* __restrict__ A, const float* __restrict__ B,
                                float* __restrict__ C) {
    int idx = blockIdx.x * 256 + threadIdx.x;
    int i = idx >> 7, j = idx & 127;
    float s = 0.f;
    for (int k = 0; k < 128; ++k) s += A[i * 128 + k] * B[k * 128 + j];
    C[idx] = s;
}

// cvec[j] = sum_k b_in[k] * W1[k,j]
__global__ void cvec_kernel(const float* __restrict__ bin, const float* __restrict__ W1,
                            float* __restrict__ cvec) {
    int j = threadIdx.x;
    float s = 0.f;
    for (int k = 0; k < 128; ++k) s += bin[k] * W1[k * 128 + j];
    cvec[j] = s;
}

// pack W[k][n] fp32 -> bf16 MFMA-B layout: Bp[((k>>3)*128 + n)*8 + (k&7)]
__global__ void pack_b_kernel(const float* __restrict__ W, ushort* __restrict__ Bp) {
    int idx = blockIdx.x * 256 + threadIdx.x;  // 64 blocks
    int k = idx >> 7, n = idx & 127;
    Bp[((size_t)(k >> 3) * 128 + n) * 8 + (k & 7)] = f2bf(W[idx]);
}

// ---------------- MFMA matmul: C[M,128](bf16) = A[M,128] @ B[128,128] ----------------
// block 256 = 4 waves, each wave 16 rows x 128 cols. A frags direct from global.
template <bool ABF16>
__global__ __launch_bounds__(256) void mm_mfma(const void* __restrict__ Av,
                                               const ushort* __restrict__ Bpack,
                                               ushort* __restrict__ C) {
    int t = threadIdx.x;
    int wave = t >> 6, lane = t & 63;
    int m = lane & 15, q = lane >> 4;
    int row = blockIdx.x * 64 + wave * 16 + m;

    short8 afr[4];
    if (ABF16) {
        const ushort* A = (const ushort*)Av;
        const ushort* ap = A + (size_t)row * 128 + q * 8;
        #pragma unroll
        for (int k0 = 0; k0 < 4; ++k0) afr[k0] = *(const short8*)(ap + k0 * 32);
    } else {
        const float* A = (const float*)Av;
        const float* ap = A + (size_t)row * 128 + q * 8;
        #pragma unroll
        for (int k0 = 0; k0 < 4; ++k0) {
            float4 f0 = *(const float4*)(ap + k0 * 32);
            float4 f1 = *(const float4*)(ap + k0 * 32 + 4);
            short8 a;
            a[0] = (short)f2bf(f0.x); a[1] = (short)f2bf(f0.y);
            a[2] = (short)f2bf(f0.z); a[3] = (short)f2bf(f0.w);
            a[4] = (short)f2bf(f1.x); a[5] = (short)f2bf(f1.y);
            a[6] = (short)f2bf(f1.z); a[7] = (short)f2bf(f1.w);
            afr[k0] = a;
        }
    }

    floatx4 acc[8];
    #pragma unroll
    for (int nt = 0; nt < 8; ++nt) {
        floatx4 z = {0.f, 0.f, 0.f, 0.f};
        acc[nt] = z;
    }

    #pragma unroll
    for (int nt = 0; nt < 8; ++nt) {
        #pragma unroll
        for (int k0 = 0; k0 < 4; ++k0) {
            short8 b = *(const short8*)(Bpack + ((size_t)(k0 * 4 + q) * 128 + nt * 16 + m) * 8);
            acc[nt] = __builtin_amdgcn_mfma_f32_16x16x32_bf16(afr[k0], b, acc[nt], 0, 0, 0);
        }
    }

    // C/D layout: col = lane&15 (=m), row = q*4 + r
    int orow_base = blockIdx.x * 64 + wave * 16 + q * 4;
    #pragma unroll
    for (int nt = 0; nt < 8; ++nt) {
        #pragma unroll
        for (int r = 0; r < 4; ++r) {
            C[(size_t)(orow_base + r) * 128 + nt * 16 + m] = f2bf(acc[nt][r]);
        }
    }
}

// ---------------- GCN aggregation: one wave per dst node, bf16 gather ----------------
__global__ __launch_bounds__(256) void agg_kernel(const ushort* __restrict__ hw,
                                                  const float* __restrict__ dis,
                                                  const int* __restrict__ rowptr,
                                                  const int* __restrict__ colv,
                                                  const float* __restrict__ cvec,
                                                  const float* __restrict__ bias,
                                                  ushort* __restrict__ out, int N) {
    int wave = (int)((blockIdx.x * 256u + threadIdx.x) >> 6);
    int lane = threadIdx.x & 63;
    if (wave >= N) return;
    int i = wave;
    float di = dis[i];
    int beg = rowptr[i], end = rowptr[i + 1];
    const uint* __restrict__ hv = (const uint*)hw;  // 2 bf16 per lane

    float sii = di * di;
    uint su = hv[(size_t)i * 64 + lane];
    float a0 = sii * bf_lo(su);
    float a1 = sii * bf_hi(su);
    float sumnorm = sii;

    int e = beg;
    for (; e + 3 < end; e += 4) {
        int s0 = colv[e], s1 = colv[e + 1], s2 = colv[e + 2], s3 = colv[e + 3];
        float n0 = dis[s0] * di, n1 = dis[s1] * di;
        float n2 = dis[s2] * di, n3 = dis[s3] * di;
        uint u0 = hv[(size_t)s0 * 64 + lane];
        uint u1 = hv[(size_t)s1 * 64 + lane];
        uint u2 = hv[(size_t)s2 * 64 + lane];
        uint u3 = hv[(size_t)s3 * 64 + lane];
        a0 = fmaf(n0, bf_lo(u0), a0); a1 = fmaf(n0, bf_hi(u0), a1);
        a0 = fmaf(n1, bf_lo(u1), a0); a1 = fmaf(n1, bf_hi(u1), a1);
        a0 = fmaf(n2, bf_lo(u2), a0); a1 = fmaf(n2, bf_hi(u2), a1);
        a0 = fmaf(n3, bf_lo(u3), a0); a1 = fmaf(n3, bf_hi(u3), a1);
        sumnorm += (n0 + n1) + (n2 + n3);
    }
    for (; e < end; ++e) {
        int s0 = colv[e];
        float n0 = dis[s0] * di;
        uint u0 = hv[(size_t)s0 * 64 + lane];
        a0 = fmaf(n0, bf_lo(u0), a0);
        a1 = fmaf(n0, bf_hi(u0), a1);
        sumnorm += n0;
    }

    float c0 = 0.f, c1 = 0.f;
    if (cvec) { c0 = cvec[2 * lane]; c1 = cvec[2 * lane + 1]; }
    float b0 = bias[2 * lane], b1 = bias[2 * lane + 1];
    float o0 = fmaxf(fmaf(sumnorm, c0, a0) + b0, 0.f);
    float o1 = fmaxf(fmaf(sumnorm, c1, a1) + b1, 0.f);
    uint o = (uint)f2bf(o0) | ((uint)f2bf(o1) << 16);
    ((uint*)out)[(size_t)i * 64 + lane] = o;
}

// ---------------- pooling: bf16 input, fp32 accumulate ----------------
__global__ __launch_bounds__(256) void pool_kernel(const ushort* __restrict__ h,
                                                   const int* __restrict__ batch,
                                                   float* __restrict__ pool, int N) {
    int t = threadIdx.x;
    int c = t & 127, half = t >> 7;
    int n0 = blockIdx.x * 256 + half * 128;
    int cur = -1;
    float acc = 0.f;
    for (int j = 0; j < 128; ++j) {
        int n = n0 + j;
        if (n >= N) break;
        int g = batch[n];
        float v = __uint_as_float((uint)h[(size_t)n * 128 + c] << 16);
        if (g != cur) {
            if (cur >= 0) atomicAdd(&pool[cur * 128 + c], acc);
            cur = g;
            acc = 0.f;
        }
        acc += v;
    }
    if (cur >= 0) atomicAdd(&pool[cur * 128 + c], acc);
}

// ---------------- final MLP head ----------------
__device__ int lower_bound_dev(const int* __restrict__ a, int n, int x) {
    int lo = 0, hi = n;
    while (lo < hi) {
        int m = (lo + hi) >> 1;
        if (a[m] < x) lo = m + 1; else hi = m;
    }
    return lo;
}

__global__ __launch_bounds__(256) void final_kernel(const float* __restrict__ pool_sum,
                                                    const int* __restrict__ batch,
                                                    const float* __restrict__ Wf1,
                                                    const float* __restrict__ bf1,
                                                    const float* __restrict__ Wf2,
                                                    const float* __restrict__ bf2,
                                                    float* __restrict__ out, int N) {
    __shared__ float pooled[16][128];
    __shared__ float z[16][64];
    __shared__ int cnt[16];
    int t = threadIdx.x;
    if (t < 16) {
        int lo = lower_bound_dev(batch, N, t);
        int hi = lower_bound_dev(batch, N, t + 1);
        cnt[t] = hi - lo;
    }
    __syncthreads();
    for (int idx = t; idx < 2048; idx += 256) {
        int g = idx >> 7, c = idx & 127;
        float cn = (float)(cnt[g] > 1 ? cnt[g] : 1);
        pooled[g][c] = pool_sum[idx] / cn;
    }
    __syncthreads();
    for (int idx = t; idx < 1024; idx += 256) {
        int g = idx >> 6, j = idx & 63;
        float s = bf1[j];
        for (int k = 0; k < 128; ++k) s = fmaf(pooled[g][k], Wf1[k * 64 + j], s);
        z[g][j] = fmaxf(s, 0.f);
    }
    __syncthreads();
    if (t < 160) {
        int g = t / 10, k = t % 10;
        float s = bf2[k];
        for (int j = 0; j < 64; ++j) s = fmaf(z[g][j], Wf2[j * 10 + k], s);
        out[t] = s;
    }
}

// ---------------- launch ----------------

extern "C" void kernel_launch(void* const* d_in, const int* in_sizes, int n_in,
                              void* d_out, int out_size, void* d_ws, size_t ws_size,
                              hipStream_t stream) {
    const float* x    = (const float*)d_in[0];
    const int* edge   = (const int*)d_in[1];   // [2, E]
    const int* batch  = (const int*)d_in[2];
    const float* W_in = (const float*)d_in[3];
    const float* b_in = (const float*)d_in[4];
    const float* W1   = (const float*)d_in[5];
    const float* b1   = (const float*)d_in[6];
    const float* W2   = (const float*)d_in[7];
    const float* b2   = (const float*)d_in[8];
    const float* Wf1  = (const float*)d_in[9];
    const float* bf1  = (const float*)d_in[10];
    const float* Wf2  = (const float*)d_in[11];
    const float* bf2  = (const float*)d_in[12];
    float* out = (float*)d_out;

    const int N = NODES, E = NEDGE;
    const int NB = (N + 255) / 256;  // 157 scan blocks

    char* ws = (char*)d_ws;
    size_t off = 0;
    auto alloc = [&](size_t bytes) -> void* {
        void* p = ws + off;
        off += (bytes + 511) & ~(size_t)511;
        return p;
    };
    ushort* bufA  = (ushort*)alloc((size_t)N * 128 * 2);  // hw1 / hw2 (bf16)
    ushort* bufB  = (ushort*)alloc((size_t)N * 128 * 2);  // h1 / h2 (bf16)
    float* Wc     = (float*)alloc(128 * 128 * 4);
    ushort* Bp1   = (ushort*)alloc(128 * 128 * 2);
    ushort* Bp2   = (ushort*)alloc(128 * 128 * 2);
    float* cvec   = (float*)alloc(128 * 4);
    float* dis    = (float*)alloc((size_t)N * 4);
    int* rowptr   = (int*)alloc((size_t)(N + 1) * 4);
    int* cursor   = (int*)alloc((size_t)N * 4);
    int* counts   = (int*)alloc((size_t)N * 4);
    int* bsum     = (int*)alloc((size_t)NB * 4);
    int* boff     = (int*)alloc((size_t)NB * 4);
    int* colbuf   = (int*)alloc((size_t)E * 4);
    float* pools  = (float*)alloc(16 * 128 * 4);

    hipMemsetAsync(counts, 0, (size_t)N * 4, stream);
    hipMemsetAsync(pools, 0, 16 * 128 * 4, stream);

    // CSR build
    hist_kernel<<<(E + 255) / 256, 256, 0, stream>>>(edge + E, counts, E);
    s1_reduce<<<NB, 256, 0, stream>>>(counts, bsum, N);
    s2_scan<<<1, 256, 0, stream>>>(bsum, boff, rowptr + N, NB);
    s3_scatter<<<NB, 256, 0, stream>>>(counts, boff, rowptr, cursor, dis, N);
    fill_kernel<<<(E + 255) / 256, 256, 0, stream>>>(edge, edge + E, cursor, colbuf, E);

    // weights prep
    small_mm_kernel<<<64, 256, 0, stream>>>(W_in, W1, Wc);   // Wc = W_in @ W1
    cvec_kernel<<<1, 128, 0, stream>>>(b_in, W1, cvec);       // cvec = b_in @ W1
    pack_b_kernel<<<64, 256, 0, stream>>>(Wc, Bp1);
    pack_b_kernel<<<64, 256, 0, stream>>>(W2, Bp2);

    // layer 1: hw1 = x @ Wc (MFMA, bf16 out); h1 = relu(S hw1 + sumnorm*cvec + b1)
    mm_mfma<false><<<N / 64, 256, 0, stream>>>(x, Bp1, bufA);
    agg_kernel<<<N / 4, 256, 0, stream>>>(bufA, dis, rowptr, colbuf, cvec, b1, bufB, N);

    // layer 2: hw2 = h1 @ W2; h2 = relu(S hw2 + b2)
    mm_mfma<true><<<N / 64, 256, 0, stream>>>(bufB, Bp2, bufA);
    agg_kernel<<<N / 4, 256, 0, stream>>>(bufA, dis, rowptr, colbuf, nullptr, b2, bufB, N);

    // mean pool + MLP head
    pool_kernel<<<NB, 256, 0, stream>>>(bufB, batch, pools, N);
    final_kernel<<<1, 256, 0, stream>>>(pools, batch, Wf1, bf1, Wf2, bf2, out, N);
}